// Round 10
// baseline (500.615 us; speedup 1.0000x reference)
//
#include <hip/hip_runtime.h>
#include <hip/hip_bf16.h>

// MoE: B=4,S=4096,D=512,E=16,H=2048,top-2. T=16384 tokens, 32768 slots.
#define T_TOK 16384
#define DDIM  512
#define NEXP  16
#define HDIM  2048
#define NSLOT (T_TOK * 2)
#define NHB   128         // histogram blocks: NSLOT / 256

#define GBM 128           // gemm tile M (matches tile table)
#define GBN 256           // gemm tile N (both gemms)
#define BK  32            // gemm K-step
#define MAXTILE 272       // max m-tiles: 32768/128 + 16
#define TSLICE  136       // m-tile slice: hbuf slice ~67 MB stays L3-resident

typedef __attribute__((ext_vector_type(8))) short short8;   // 8 x bf16
typedef __attribute__((ext_vector_type(4))) short short4v;
typedef __attribute__((ext_vector_type(4))) float f32x4;

__device__ inline short f2bf(float f) {
    __hip_bfloat16 h = __float2bfloat16(f);
    return *reinterpret_cast<short*>(&h);
}
__device__ inline float bf2f(short s) {
    unsigned u = ((unsigned)(unsigned short)s) << 16;
    union { unsigned u; float f; } c; c.u = u; return c.f;
}
// A&S 7.1.26 erf: |abs err| < 1.5e-7 (<< bf16 rounding of hbuf). ~14 VALU ops.
__device__ inline float erf_fast(float x) {
    float ax = fabsf(x);
    float t = 1.0f / fmaf(0.3275911f, ax, 1.0f);
    float p = fmaf(fmaf(fmaf(fmaf(1.061405429f, t, -1.453152027f), t,
                  1.421413741f), t, -0.284496736f), t, 0.254829592f) * t;
    float r = 1.0f - p * __expf(-ax * ax);
    return copysignf(r, x);
}
__device__ inline float geluf(float v) {   // exact-form gelu via fast erf
    return 0.5f * v * (1.0f + erf_fast(v * 0.70710678118654752440f));
}
// async global->LDS, 16B per lane. LDS dest = WAVE-UNIFORM base + lane*16.
__device__ inline void gload16(const void* g, void* l) {
    __builtin_amdgcn_global_load_lds(
        (const __attribute__((address_space(1))) void*)g,
        (__attribute__((address_space(3))) void*)l, 16, 0, 0);
}

// ---------------- routing ----------------
// wave-per-token gate: lane (g,q) = (d-quarter, expert). fp64 (tie-robust).
__global__ __launch_bounds__(256) void gate_kernel(
    const float* __restrict__ x, const float* __restrict__ wg,
    const float* __restrict__ bg, int* __restrict__ tok_e,
    float* __restrict__ tok_w)
{
    int wv = threadIdx.x >> 6, lane = threadIdx.x & 63;
    int t = blockIdx.x * 4 + wv;
    int g = lane >> 4, q = lane & 15;
    const float* xr = x + (size_t)t * DDIM + g * 128;
    const float* wr = wg + (size_t)g * 128 * NEXP + q;
    double a0 = 0, a1 = 0, a2 = 0, a3 = 0;
#pragma unroll
    for (int c = 0; c < 8; ++c) {
        float4 v0 = ((const float4*)xr)[c * 4 + 0];
        float4 v1 = ((const float4*)xr)[c * 4 + 1];
        float4 v2 = ((const float4*)xr)[c * 4 + 2];
        float4 v3 = ((const float4*)xr)[c * 4 + 3];
        const float* wp = wr + c * 16 * NEXP;
        a0 += (double)v0.x * (double)wp[0 * NEXP];
        a1 += (double)v0.y * (double)wp[1 * NEXP];
        a2 += (double)v0.z * (double)wp[2 * NEXP];
        a3 += (double)v0.w * (double)wp[3 * NEXP];
        a0 += (double)v1.x * (double)wp[4 * NEXP];
        a1 += (double)v1.y * (double)wp[5 * NEXP];
        a2 += (double)v1.z * (double)wp[6 * NEXP];
        a3 += (double)v1.w * (double)wp[7 * NEXP];
        a0 += (double)v2.x * (double)wp[8 * NEXP];
        a1 += (double)v2.y * (double)wp[9 * NEXP];
        a2 += (double)v2.z * (double)wp[10 * NEXP];
        a3 += (double)v2.w * (double)wp[11 * NEXP];
        a0 += (double)v3.x * (double)wp[12 * NEXP];
        a1 += (double)v3.y * (double)wp[13 * NEXP];
        a2 += (double)v3.z * (double)wp[14 * NEXP];
        a3 += (double)v3.w * (double)wp[15 * NEXP];
    }
    double a = ((a0 + a1) + (a2 + a3));
    a += __shfl_xor(a, 16, 64);
    a += __shfl_xor(a, 32, 64);
    a += (double)bg[q];
    double v0 = a; int i0 = q;
#pragma unroll
    for (int s = 1; s < 16; s <<= 1) {
        double ov = __shfl_xor(v0, s, 64);
        int oi = __shfl_xor(i0, s, 64);
        if (ov > v0 || (ov == v0 && oi < i0)) { v0 = ov; i0 = oi; }
    }
    double m2 = (q == i0) ? -1e300 : a;
    double v1 = m2; int i1 = q;
#pragma unroll
    for (int s = 1; s < 16; s <<= 1) {
        double ov = __shfl_xor(v1, s, 64);
        int oi = __shfl_xor(i1, s, 64);
        if (ov > v1 || (ov == v1 && oi < i1)) { v1 = ov; i1 = oi; }
    }
    if (lane == 0) {
        float ex = expf((float)(v1 - v0));      // <= 1
        float w0 = 1.0f / (1.0f + ex);
        tok_e[2 * t] = i0; tok_e[2 * t + 1] = i1;
        tok_w[2 * t] = w0; tok_w[2 * t + 1] = ex * w0;
    }
}

// per-block expert histogram (LDS atomics only)
__global__ __launch_bounds__(256) void hist_kernel(
    const int* __restrict__ tok_e, int* __restrict__ bhist)
{
    __shared__ int h[NEXP];
    if (threadIdx.x < NEXP) h[threadIdx.x] = 0;
    __syncthreads();
    atomicAdd(&h[tok_e[blockIdx.x * 256 + threadIdx.x]], 1);
    __syncthreads();
    if (threadIdx.x < NEXP) bhist[blockIdx.x * NEXP + threadIdx.x] = h[threadIdx.x];
}

// offs[0..16] = exclusive scan; offs[17] = ntiles; bbase[b][e] = scatter base.
__global__ void scan_kernel(const int* __restrict__ bhist, int* __restrict__ offs,
                            int* __restrict__ bbase, int* __restrict__ tile_e,
                            int* __restrict__ tile_m0)
{
    int tid = threadIdx.x;
    __shared__ int tot[NEXP];
    if (tid < NEXP) {
        int s = 0;
        for (int b = 0; b < NHB; ++b) s += bhist[b * NEXP + tid];
        tot[tid] = s;
    }
    __syncthreads();
    if (tid == 0) {
        int run = 0;
        for (int e = 0; e < NEXP; ++e) { offs[e] = run; run += tot[e]; }
        offs[NEXP] = run;   // == NSLOT
        int nt = 0;
        for (int e = 0; e < NEXP; ++e)
            for (int m = offs[e]; m < offs[e + 1]; m += GBM) {
                tile_e[nt] = e; tile_m0[nt] = m; ++nt;
            }
        offs[17] = nt;
    }
    __syncthreads();
    if (tid < NEXP) {
        int run = offs[tid];
        for (int b = 0; b < NHB; ++b) {
            bbase[b * NEXP + tid] = run;
            run += bhist[b * NEXP + tid];
        }
    }
}

// local rank via LDS atomic + precomputed block base
__global__ __launch_bounds__(256) void scatter_kernel(
    const int* __restrict__ tok_e, const float* __restrict__ tok_w,
    const int* __restrict__ bbase, int* __restrict__ list_tok,
    float* __restrict__ list_w, int* __restrict__ pos_tk)
{
    __shared__ int h[NEXP];
    if (threadIdx.x < NEXP) h[threadIdx.x] = 0;
    __syncthreads();
    int s = blockIdx.x * 256 + threadIdx.x;
    int e = tok_e[s];
    int r = atomicAdd(&h[e], 1);
    int pos = bbase[blockIdx.x * NEXP + e] + r;
    list_tok[pos] = s >> 1;
    list_w[pos] = tok_w[s];
    pos_tk[s] = pos;
}

// ---------------- pre-conversion ----------------

__global__ void cvt_bf16_kernel(const float* __restrict__ src, short* __restrict__ dst, int n4)
{
    int i = blockIdx.x * blockDim.x + threadIdx.x;
    int stride = gridDim.x * blockDim.x;
    for (; i < n4; i += stride) {
        float4 v = ((const float4*)src)[i];
        short4v o;
        o[0] = f2bf(v.x); o[1] = f2bf(v.y); o[2] = f2bf(v.z); o[3] = f2bf(v.w);
        ((short4v*)dst)[i] = o;
    }
}

// transpose one [R][C] fp32 matrix per blockIdx.z into [C][R] bf16
__global__ void wtrans_kernel(const float* __restrict__ src, short* __restrict__ dst, int R, int C)
{
    __shared__ float t[32][33];
    int c0 = blockIdx.x * 32, r0 = blockIdx.y * 32;
    const float* s = src + (size_t)blockIdx.z * R * C;
    short* d = dst + (size_t)blockIdx.z * R * C;
    int cc = threadIdx.x & 31, rr = threadIdx.x >> 5;
#pragma unroll
    for (int pp = 0; pp < 4; ++pp)
        t[rr + pp * 8][cc] = s[(size_t)(r0 + rr + pp * 8) * C + c0 + cc];
    __syncthreads();
#pragma unroll
    for (int pp = 0; pp < 4; ++pp) {
        int c = rr + pp * 8;
        d[(size_t)(c0 + c) * R + r0 + cc] = f2bf(t[cc][c]);
    }
}

// ---------------- expert GEMMs: counted-vmcnt 3-buffer pipeline ----------------
// 128x256 tile, BK=32, 256 threads = 4 waves (2M x 2N), wave-tile 64x128:
// per K-step each wave does 12 ds_read_b128 (4A+8B) feeding 32 MFMA — round-9's
// 64x64 wave-tile spent more LDS-read time (8 reads/16 MFMA) than matrix time.
// LDS 73 KB -> 2 blk/CU (8 waves). Per K-step: counted vmcnt(6) -> raw
// s_barrier -> sched_barrier(0) -> stage(t+2) -> frag reads -> setprio MFMA.
// T2 swizzle both-sides (pre-swizzled gather source + swizzled read).

__global__ __launch_bounds__(256, 2) void gemm1_kernel(
    const short* __restrict__ xbf, const short* __restrict__ w1t,
    const float* __restrict__ b1, const int* __restrict__ offs,
    const int* __restrict__ tile_e, const int* __restrict__ tile_m0,
    const int* __restrict__ list_tok, short* __restrict__ hbuf,
    int h0, int hlen, int t0)
{
    int tb = t0 + (int)blockIdx.y;      // tile index (grid y: slow)
    if (tb >= offs[17]) return;
    int e = tile_e[tb], m0 = tile_m0[tb];
    int rows = offs[e + 1] - m0; if (rows > GBM) rows = GBM;
    int n0 = blockIdx.x * GBN;          // n-chunk (grid x: fast -> L2 share)
    int tid = threadIdx.x, l = tid & 63, w = tid >> 6;

    __shared__ __align__(16) short As[3][GBM * BK];   // 3 x 8 KiB
    __shared__ __align__(16) short Bs[3][GBN * BK];   // 3 x 16 KiB
    __shared__ int ts[GBM];
    if (tid < GBM) ts[tid] = list_tok[m0 + (tid < rows ? tid : rows - 1)];
    __syncthreads();

    // A staging: wave w rows [w*32,+32), 2 instr; B: rows [w*64,+64), 4 instr
    int ar0 = w * 32 + (l >> 2), ar1 = ar0 + 16;
    int as0 = (l & 3) ^ ((ar0 >> 1) & 3), as1 = (l & 3) ^ ((ar1 >> 1) & 3);
    const short* gA0 = xbf + (size_t)ts[ar0] * DDIM + as0 * 8;
    const short* gA1 = xbf + (size_t)ts[ar1] * DDIM + as1 * 8;
    const short* gB[4];
#pragma unroll
    for (int i = 0; i < 4; ++i) {
        int br = w * 64 + i * 16 + (l >> 2);
        int bs = (l & 3) ^ ((br >> 1) & 3);
        gB[i] = w1t + ((size_t)e * HDIM + (size_t)(h0 + n0 + br)) * DDIM + bs * 8;
    }

    int l15 = l & 15, kq = l >> 4;
    int wm = w >> 1, wn = w & 1;
    int aoff[4], boff[8];
#pragma unroll
    for (int mi = 0; mi < 4; ++mi) {
        int R = wm * 64 + mi * 16 + l15;
        aoff[mi] = R * BK + ((kq ^ ((R >> 1) & 3)) * 8);
    }
#pragma unroll
    for (int ni = 0; ni < 8; ++ni) {
        int S = wn * 128 + ni * 16 + l15;
        boff[ni] = S * BK + ((kq ^ ((S >> 1) & 3)) * 8);
    }

    f32x4 vzero = {0.0f, 0.0f, 0.0f, 0.0f};
    f32x4 acc[4][8];
#pragma unroll
    for (int i = 0; i < 4; ++i)
#pragma unroll
        for (int j = 0; j < 8; ++j) acc[i][j] = vzero;

#define STAGE1(T, B) {                                            \
        gload16(gA0 + (T) * BK, &As[B][w * 1024]);                \
        gload16(gA1 + (T) * BK, &As[B][w * 1024 + 512]);          \
        _Pragma("unroll")                                         \
        for (int i = 0; i < 4; ++i)                               \
            gload16(gB[i] + (T) * BK, &Bs[B][w * 2048 + i * 512]); }

    const int nt = DDIM / BK;          // 16
    STAGE1(0, 0);
    STAGE1(1, 1);
    int cb = 0, sb = 2;
#pragma unroll 1
    for (int t = 0; t < nt; ++t) {
        if (t < nt - 1) asm volatile("s_waitcnt vmcnt(6)" ::: "memory");
        else            asm volatile("s_waitcnt vmcnt(0)" ::: "memory");
        __builtin_amdgcn_s_barrier();
        __builtin_amdgcn_sched_barrier(0);
        if (t + 2 < nt) STAGE1(t + 2, sb);
        const short* Ab = &As[cb][0];
        const short* Bb = &Bs[cb][0];
        short8 af[4], bv[8];
#pragma unroll
        for (int mi = 0; mi < 4; ++mi) af[mi] = *(const short8*)(Ab + aoff[mi]);
#pragma unroll
        for (int ni = 0; ni < 8; ++ni) bv[ni] = *(const short8*)(Bb + boff[ni]);
        __builtin_amdgcn_s_setprio(1);
#pragma unroll
        for (int mi = 0; mi < 4; ++mi)
#pragma unroll
            for (int ni = 0; ni < 8; ++ni)
                acc[mi][ni] = __builtin_amdgcn_mfma_f32_16x16x32_bf16(
                    af[mi], bv[ni], acc[mi][ni], 0, 0, 0);
        __builtin_amdgcn_s_setprio(0);
        cb = (cb == 2) ? 0 : cb + 1;
        sb = (sb == 2) ? 0 : sb + 1;
    }
#undef STAGE1

    int crow = wm * 64 + (kq << 2);
    int ccol = wn * 128 + l15;
#pragma unroll
    for (int mi = 0; mi < 4; ++mi) {
#pragma unroll
        for (int ni = 0; ni < 8; ++ni) {
            int col = ccol + ni * 16;
            float bias = b1[e * HDIM + h0 + n0 + col];
#pragma unroll
            for (int j = 0; j < 4; ++j) {
                int row = crow + mi * 16 + j;
                if (row < rows) {
                    float v = acc[mi][ni][j] + bias;
                    hbuf[(size_t)(m0 + row) * hlen + (n0 + col)] = f2bf(geluf(v));
                }
            }
        }
    }
}

__global__ __launch_bounds__(256, 2) void gemm2_kernel(
    const short* __restrict__ hbuf, const short* __restrict__ w2t,
    const float* __restrict__ b2, const int* __restrict__ offs,
    const int* __restrict__ tile_e, const int* __restrict__ tile_m0,
    const int* __restrict__ list_tok, const float* __restrict__ list_w,
    short* __restrict__ ybuf, float* __restrict__ out,
    int h0, int hlen, int mode, int t0)
{
    int tb = t0 + (int)blockIdx.y;
    if (tb >= offs[17]) return;
    int e = tile_e[tb], m0 = tile_m0[tb];
    int rows = offs[e + 1] - m0; if (rows > GBM) rows = GBM;
    int n0 = blockIdx.x * GBN;           // output d coordinate (grid x = 2)
    int tid = threadIdx.x, l = tid & 63, w = tid >> 6;

    __shared__ __align__(16) short As[3][GBM * BK];
    __shared__ __align__(16) short Bs[3][GBN * BK];
    __shared__ int ts[GBM];
    __shared__ float lw[GBM];
    if (tid < GBM) {
        int idx = m0 + (tid < rows ? tid : rows - 1);
        ts[tid] = list_tok[idx];
        lw[tid] = list_w[idx];
    }
    __syncthreads();

    int ar0 = w * 32 + (l >> 2), ar1 = ar0 + 16;
    int as0 = (l & 3) ^ ((ar0 >> 1) & 3), as1 = (l & 3) ^ ((ar1 >> 1) & 3);
    int ag0 = m0 + ar0; if (ag0 >= NSLOT) ag0 = NSLOT - 1;
    int ag1 = m0 + ar1; if (ag1 >= NSLOT) ag1 = NSLOT - 1;
    const short* gA0 = hbuf + (size_t)ag0 * hlen + as0 * 8;
    const short* gA1 = hbuf + (size_t)ag1 * hlen + as1 * 8;
    const short* gB[4];
#pragma unroll
    for (int i = 0; i < 4; ++i) {
        int br = w * 64 + i * 16 + (l >> 2);
        int bs = (l & 3) ^ ((br >> 1) & 3);
        gB[i] = w2t + ((size_t)e * DDIM + (size_t)(n0 + br)) * HDIM + h0 + bs * 8;
    }

    int l15 = l & 15, kq = l >> 4;
    int wm = w >> 1, wn = w & 1;
    int aoff[4], boff[8];
#pragma unroll
    for (int mi = 0; mi < 4; ++mi) {
        int R = wm * 64 + mi * 16 + l15;
        aoff[mi] = R * BK + ((kq ^ ((R >> 1) & 3)) * 8);
    }
#pragma unroll
    for (int ni = 0; ni < 8; ++ni) {
        int S = wn * 128 + ni * 16 + l15;
        boff[ni] = S * BK + ((kq ^ ((S >> 1) & 3)) * 8);
    }

    f32x4 vzero = {0.0f, 0.0f, 0.0f, 0.0f};
    f32x4 acc[4][8];
#pragma unroll
    for (int i = 0; i < 4; ++i)
#pragma unroll
        for (int j = 0; j < 8; ++j) acc[i][j] = vzero;

#define STAGE2(T, B) {                                            \
        gload16(gA0 + (T) * BK, &As[B][w * 1024]);                \
        gload16(gA1 + (T) * BK, &As[B][w * 1024 + 512]);          \
        _Pragma("unroll")                                         \
        for (int i = 0; i < 4; ++i)                               \
            gload16(gB[i] + (T) * BK, &Bs[B][w * 2048 + i * 512]); }

    const int nt = hlen / BK;          // 64 at hlen=2048
    STAGE2(0, 0);
    STAGE2(1, 1);
    int cb = 0, sb = 2;
#pragma unroll 1
    for (int t = 0; t < nt; ++t) {
        if (t < nt - 1) asm volatile("s_waitcnt vmcnt(6)" ::: "memory");
        else            asm volatile("s_waitcnt vmcnt(0)" ::: "memory");
        __builtin_amdgcn_s_barrier();
        __builtin_amdgcn_sched_barrier(0);
        if (t + 2 < nt) STAGE2(t + 2, sb);
        const short* Ab = &As[cb][0];
        const short* Bb = &Bs[cb][0];
        short8 af[4], bv[8];
#pragma unroll
        for (int mi = 0; mi < 4; ++mi) af[mi] = *(const short8*)(Ab + aoff[mi]);
#pragma unroll
        for (int ni = 0; ni < 8; ++ni) bv[ni] = *(const short8*)(Bb + boff[ni]);
        __builtin_amdgcn_s_setprio(1);
#pragma unroll
        for (int mi = 0; mi < 4; ++mi)
#pragma unroll
            for (int ni = 0; ni < 8; ++ni)
                acc[mi][ni] = __builtin_amdgcn_mfma_f32_16x16x32_bf16(
                    af[mi], bv[ni], acc[mi][ni], 0, 0, 0);
        __builtin_amdgcn_s_setprio(0);
        cb = (cb == 2) ? 0 : cb + 1;
        sb = (sb == 2) ? 0 : sb + 1;
    }
#undef STAGE2

    int crow = wm * 64 + (kq << 2);
    int ccol = wn * 128 + l15;
#pragma unroll
    for (int mi = 0; mi < 4; ++mi) {
#pragma unroll
        for (int ni = 0; ni < 8; ++ni) {
            int col = ccol + ni * 16;
            float bias = (h0 == 0) ? b2[e * DDIM + n0 + col] : 0.0f;
#pragma unroll
            for (int j = 0; j < 4; ++j) {
                int row = crow + mi * 16 + j;
                if (row < rows) {
                    float v = acc[mi][ni][j] + bias;
                    if (mode == 0)   // full-K path: single bf16 write
                        ybuf[(size_t)(m0 + row) * DDIM + n0 + col] = f2bf(v);
                    else
                        atomicAdd(&out[(size_t)ts[row] * DDIM + n0 + col], lw[row] * v);
                }
            }
        }
    }
}

// out[t] = w0*ybuf[pos0] + w1*ybuf[pos1]  (ybuf bf16, 8 cols/thread)
__global__ __launch_bounds__(256) void combine_kernel(
    const short* __restrict__ ybuf, const int* __restrict__ pos_tk,
    const float* __restrict__ tok_w, float* __restrict__ out)
{
    int i = blockIdx.x * 256 + threadIdx.x;   // over T_TOK * 64 units
    int t = i >> 6, c = (i & 63) * 8;
    float w0 = tok_w[2 * t], w1 = tok_w[2 * t + 1];
    int p0 = pos_tk[2 * t], p1 = pos_tk[2 * t + 1];
    short8 a = *(const short8*)(ybuf + (size_t)p0 * DDIM + c);
    short8 b = *(const short8*)(ybuf + (size_t)p1 * DDIM + c);
    float4 o0, o1;
    float* op = (float*)&o0;
#pragma unroll
    for (int j = 0; j < 4; ++j) op[j] = w0 * bf2f(a[j]) + w1 * bf2f(b[j]);
    float* op1 = (float*)&o1;
#pragma unroll
    for (int j = 0; j < 4; ++j) op1[j] = w0 * bf2f(a[4 + j]) + w1 * bf2f(b[4 + j]);
    float4* ob = (float4*)(out + (size_t)t * DDIM + c);
    ob[0] = o0;
    ob[1] = o1;
}

// ---------------- launch ----------------

extern "C" void kernel_launch(void* const* d_in, const int* in_sizes, int n_in,
                              void* d_out, int out_size, void* d_ws, size_t ws_size,
                              hipStream_t stream)
{
    const float* x  = (const float*)d_in[0];
    const float* wg = (const float*)d_in[1];
    const float* bg = (const float*)d_in[2];
    const float* w1 = (const float*)d_in[3];
    const float* b1 = (const float*)d_in[4];
    const float* w2 = (const float*)d_in[5];
    const float* b2 = (const float*)d_in[6];
    float* out = (float*)d_out;

    char* p = (char*)d_ws;
    int* offs     = (int*)(p + 128);            // 32 ints
    int* tile_e   = (int*)(p + 256);            // 512 ints
    int* tile_m0  = (int*)(p + 2304);           // 512 ints
    int* bhist    = (int*)(p + 8192);           // 8 KiB
    int* bbase    = (int*)(p + 16384);          // 8 KiB
    int* tok_e    = (int*)(p + 32768);          // 128 KiB
    float* tok_w  = (float*)(p + 32768 + 131072);
    int* list_tok = (int*)(p + 32768 + 262144);
    float* list_w = (float*)(p + 32768 + 393216);
    int* pos_tk   = (int*)(p + 32768 + 524288);
    short* xbf    = (short*)(p + 32768 + 655360);             // 16 MiB
    short* w1t    = xbf + (size_t)T_TOK * DDIM;               // 32 MiB
    short* w2t    = w1t + (size_t)NEXP * DDIM * HDIM;         // 32 MiB
    char* after   = (char*)(w2t + (size_t)NEXP * DDIM * HDIM);
    size_t fixed  = (size_t)(after - p);

    // mode 0: full-K gemm2 + bf16 ybuf + combine (needs hbuf 134 MB + ybuf 33.5 MB)
    // mode 1 fallback: h-chunked gemm2 with atomic out accumulate.
    int mode, hlen = HDIM;
    if (fixed + (size_t)NSLOT * DDIM * 2 + (size_t)NSLOT * HDIM * 2 <= ws_size) {
        mode = 0;
    } else {
        mode = 1;
        hlen = 0;
        for (int hl = HDIM; hl >= 128; hl >>= 1)
            if (fixed + (size_t)NSLOT * hl * 2 <= ws_size) { hlen = hl; break; }
    }
    short* ybuf = (short*)after;
    short* hbuf = (mode == 0) ? (short*)(after + (size_t)NSLOT * DDIM * 2) : (short*)after;

    if (!hlen) { hipMemsetAsync(d_out, 0, (size_t)out_size * sizeof(float), stream); return; }
    if (mode == 1) hipMemsetAsync(d_out, 0, (size_t)out_size * sizeof(float), stream);

    gate_kernel<<<T_TOK / 4, 256, 0, stream>>>(x, wg, bg, tok_e, tok_w);
    hist_kernel<<<NHB, 256, 0, stream>>>(tok_e, bhist);
    scan_kernel<<<1, 64, 0, stream>>>(bhist, offs, bbase, tile_e, tile_m0);
    scatter_kernel<<<NHB, 256, 0, stream>>>(tok_e, tok_w, bbase, list_tok, list_w, pos_tk);
    cvt_bf16_kernel<<<2048, 256, 0, stream>>>(x, xbf, T_TOK * DDIM / 4);
    wtrans_kernel<<<dim3(HDIM / 32, DDIM / 32, NEXP), 256, 0, stream>>>(w1, w1t, DDIM, HDIM);
    wtrans_kernel<<<dim3(DDIM / 32, HDIM / 32, NEXP), 256, 0, stream>>>(w2, w2t, HDIM, DDIM);

    // m-tile slices: gemm2(slice) consumes hbuf(slice) while it is L3-hot.
    // grid.x = n-chunk (fastest) so co-resident blocks share X / W panels.
    for (int h0 = 0; h0 < HDIM; h0 += hlen) {
        for (int t0 = 0; t0 < MAXTILE; t0 += TSLICE) {
            int tc = MAXTILE - t0; if (tc > TSLICE) tc = TSLICE;
            gemm1_kernel<<<dim3(hlen / GBN, tc), 256, 0, stream>>>(
                xbf, w1t, b1, offs, tile_e, tile_m0, list_tok, hbuf, h0, hlen, t0);
            gemm2_kernel<<<dim3(DDIM / GBN, tc), 256, 0, stream>>>(
                hbuf, w2t, b2, offs, tile_e, tile_m0, list_tok, list_w,
                ybuf, out, h0, hlen, mode, t0);
        }
    }
    if (mode == 0)
        combine_kernel<<<T_TOK * 64 / 256, 256, 0, stream>>>(ybuf, pos_tk, tok_w, out);
}

// Round 11
// 400.340 us; speedup vs baseline: 1.2505x; 1.2505x over previous
//
#include <hip/hip_runtime.h>
#include <hip/hip_bf16.h>

// MoE: B=4,S=4096,D=512,E=16,H=2048,top-2. T=16384 tokens, 32768 slots.
#define T_TOK 16384
#define DDIM  512
#define NEXP  16
#define HDIM  2048
#define NSLOT (T_TOK * 2)
#define NHB   128         // histogram blocks: NSLOT / 256

#define GBM 128           // gemm tile M (matches tile table)
#define GBN 256           // gemm1 tile N
#define GBN2 128          // gemm2 tile N (3 blk/CU + 544 blocks/slice)
#define BK  32            // gemm K-step
#define MAXTILE 272       // max m-tiles: 32768/128 + 16
#define TSLICE  136       // m-tile slice: hbuf slice ~67 MB stays L3-resident

typedef __attribute__((ext_vector_type(8))) short short8;   // 8 x bf16
typedef __attribute__((ext_vector_type(4))) short short4v;
typedef __attribute__((ext_vector_type(4))) float f32x4;

__device__ inline short f2bf(float f) {
    __hip_bfloat16 h = __float2bfloat16(f);
    return *reinterpret_cast<short*>(&h);
}
__device__ inline float bf2f(short s) {
    unsigned u = ((unsigned)(unsigned short)s) << 16;
    union { unsigned u; float f; } c; c.u = u; return c.f;
}
// A&S 7.1.26 erf: |abs err| < 1.5e-7 (<< bf16 rounding of hbuf). ~14 VALU ops.
__device__ inline float erf_fast(float x) {
    float ax = fabsf(x);
    float t = 1.0f / fmaf(0.3275911f, ax, 1.0f);
    float p = fmaf(fmaf(fmaf(fmaf(1.061405429f, t, -1.453152027f), t,
                  1.421413741f), t, -0.284496736f), t, 0.254829592f) * t;
    float r = 1.0f - p * __expf(-ax * ax);
    return copysignf(r, x);
}
__device__ inline float geluf(float v) {   // exact-form gelu via fast erf
    return 0.5f * v * (1.0f + erf_fast(v * 0.70710678118654752440f));
}
// async global->LDS, 16B per lane. LDS dest = WAVE-UNIFORM base + lane*16.
__device__ inline void gload16(const void* g, void* l) {
    __builtin_amdgcn_global_load_lds(
        (const __attribute__((address_space(1))) void*)g,
        (__attribute__((address_space(3))) void*)l, 16, 0, 0);
}
// XCD-aware decode of a 1-D grid (lin over nx*tc blocks) into (tile y, chunk xn).
// HW assigns XCD = linear_wg_id % 8; putting a tile's blocks at equal lin%8
// keeps all its n-chunks on ONE XCD -> A-tile L2-resident (round-10 pm: the
// (x,y) grid spread each tile across all 8 XCDs, re-fetching X from HBM).
__device__ inline void xcd_decode(int lin, int nx, int tc, int& y, int& xn) {
    if ((tc & 7) == 0) {
        int tpx = tc >> 3;
        int k = lin & 7, j = lin >> 3;
        y = k * tpx + j % tpx;
        xn = j / tpx;
    } else {
        xn = lin % nx;
        y = lin / nx;
    }
}

// ---------------- routing ----------------
// wave-per-token gate: lane (g,q) = (d-quarter, expert). fp64 (tie-robust).
__global__ __launch_bounds__(256) void gate_kernel(
    const float* __restrict__ x, const float* __restrict__ wg,
    const float* __restrict__ bg, int* __restrict__ tok_e,
    float* __restrict__ tok_w)
{
    int wv = threadIdx.x >> 6, lane = threadIdx.x & 63;
    int t = blockIdx.x * 4 + wv;
    int g = lane >> 4, q = lane & 15;
    const float* xr = x + (size_t)t * DDIM + g * 128;
    const float* wr = wg + (size_t)g * 128 * NEXP + q;
    double a0 = 0, a1 = 0, a2 = 0, a3 = 0;
#pragma unroll
    for (int c = 0; c < 8; ++c) {
        float4 v0 = ((const float4*)xr)[c * 4 + 0];
        float4 v1 = ((const float4*)xr)[c * 4 + 1];
        float4 v2 = ((const float4*)xr)[c * 4 + 2];
        float4 v3 = ((const float4*)xr)[c * 4 + 3];
        const float* wp = wr + c * 16 * NEXP;
        a0 += (double)v0.x * (double)wp[0 * NEXP];
        a1 += (double)v0.y * (double)wp[1 * NEXP];
        a2 += (double)v0.z * (double)wp[2 * NEXP];
        a3 += (double)v0.w * (double)wp[3 * NEXP];
        a0 += (double)v1.x * (double)wp[4 * NEXP];
        a1 += (double)v1.y * (double)wp[5 * NEXP];
        a2 += (double)v1.z * (double)wp[6 * NEXP];
        a3 += (double)v1.w * (double)wp[7 * NEXP];
        a0 += (double)v2.x * (double)wp[8 * NEXP];
        a1 += (double)v2.y * (double)wp[9 * NEXP];
        a2 += (double)v2.z * (double)wp[10 * NEXP];
        a3 += (double)v2.w * (double)wp[11 * NEXP];
        a0 += (double)v3.x * (double)wp[12 * NEXP];
        a1 += (double)v3.y * (double)wp[13 * NEXP];
        a2 += (double)v3.z * (double)wp[14 * NEXP];
        a3 += (double)v3.w * (double)wp[15 * NEXP];
    }
    double a = ((a0 + a1) + (a2 + a3));
    a += __shfl_xor(a, 16, 64);
    a += __shfl_xor(a, 32, 64);
    a += (double)bg[q];
    double v0 = a; int i0 = q;
#pragma unroll
    for (int s = 1; s < 16; s <<= 1) {
        double ov = __shfl_xor(v0, s, 64);
        int oi = __shfl_xor(i0, s, 64);
        if (ov > v0 || (ov == v0 && oi < i0)) { v0 = ov; i0 = oi; }
    }
    double m2 = (q == i0) ? -1e300 : a;
    double v1 = m2; int i1 = q;
#pragma unroll
    for (int s = 1; s < 16; s <<= 1) {
        double ov = __shfl_xor(v1, s, 64);
        int oi = __shfl_xor(i1, s, 64);
        if (ov > v1 || (ov == v1 && oi < i1)) { v1 = ov; i1 = oi; }
    }
    if (lane == 0) {
        float ex = expf((float)(v1 - v0));      // <= 1
        float w0 = 1.0f / (1.0f + ex);
        tok_e[2 * t] = i0; tok_e[2 * t + 1] = i1;
        tok_w[2 * t] = w0; tok_w[2 * t + 1] = ex * w0;
    }
}

// per-block expert histogram (LDS atomics only)
__global__ __launch_bounds__(256) void hist_kernel(
    const int* __restrict__ tok_e, int* __restrict__ bhist)
{
    __shared__ int h[NEXP];
    if (threadIdx.x < NEXP) h[threadIdx.x] = 0;
    __syncthreads();
    atomicAdd(&h[tok_e[blockIdx.x * 256 + threadIdx.x]], 1);
    __syncthreads();
    if (threadIdx.x < NEXP) bhist[blockIdx.x * NEXP + threadIdx.x] = h[threadIdx.x];
}

// offs[0..16] = exclusive scan; offs[17] = ntiles; bbase[b][e] = scatter base.
__global__ void scan_kernel(const int* __restrict__ bhist, int* __restrict__ offs,
                            int* __restrict__ bbase, int* __restrict__ tile_e,
                            int* __restrict__ tile_m0)
{
    int tid = threadIdx.x;
    __shared__ int tot[NEXP];
    if (tid < NEXP) {
        int s = 0;
        for (int b = 0; b < NHB; ++b) s += bhist[b * NEXP + tid];
        tot[tid] = s;
    }
    __syncthreads();
    if (tid == 0) {
        int run = 0;
        for (int e = 0; e < NEXP; ++e) { offs[e] = run; run += tot[e]; }
        offs[NEXP] = run;   // == NSLOT
        int nt = 0;
        for (int e = 0; e < NEXP; ++e)
            for (int m = offs[e]; m < offs[e + 1]; m += GBM) {
                tile_e[nt] = e; tile_m0[nt] = m; ++nt;
            }
        offs[17] = nt;
    }
    __syncthreads();
    if (tid < NEXP) {
        int run = offs[tid];
        for (int b = 0; b < NHB; ++b) {
            bbase[b * NEXP + tid] = run;
            run += bhist[b * NEXP + tid];
        }
    }
}

// local rank via LDS atomic + precomputed block base
__global__ __launch_bounds__(256) void scatter_kernel(
    const int* __restrict__ tok_e, const float* __restrict__ tok_w,
    const int* __restrict__ bbase, int* __restrict__ list_tok,
    float* __restrict__ list_w, int* __restrict__ pos_tk)
{
    __shared__ int h[NEXP];
    if (threadIdx.x < NEXP) h[threadIdx.x] = 0;
    __syncthreads();
    int s = blockIdx.x * 256 + threadIdx.x;
    int e = tok_e[s];
    int r = atomicAdd(&h[e], 1);
    int pos = bbase[blockIdx.x * NEXP + e] + r;
    list_tok[pos] = s >> 1;
    list_w[pos] = tok_w[s];
    pos_tk[s] = pos;
}

// ---------------- pre-conversion ----------------

__global__ void cvt_bf16_kernel(const float* __restrict__ src, short* __restrict__ dst, int n4)
{
    int i = blockIdx.x * blockDim.x + threadIdx.x;
    int stride = gridDim.x * blockDim.x;
    for (; i < n4; i += stride) {
        float4 v = ((const float4*)src)[i];
        short4v o;
        o[0] = f2bf(v.x); o[1] = f2bf(v.y); o[2] = f2bf(v.z); o[3] = f2bf(v.w);
        ((short4v*)dst)[i] = o;
    }
}

// transpose one [R][C] fp32 matrix per blockIdx.z into [C][R] bf16
__global__ void wtrans_kernel(const float* __restrict__ src, short* __restrict__ dst, int R, int C)
{
    __shared__ float t[32][33];
    int c0 = blockIdx.x * 32, r0 = blockIdx.y * 32;
    const float* s = src + (size_t)blockIdx.z * R * C;
    short* d = dst + (size_t)blockIdx.z * R * C;
    int cc = threadIdx.x & 31, rr = threadIdx.x >> 5;
#pragma unroll
    for (int pp = 0; pp < 4; ++pp)
        t[rr + pp * 8][cc] = s[(size_t)(r0 + rr + pp * 8) * C + c0 + cc];
    __syncthreads();
#pragma unroll
    for (int pp = 0; pp < 4; ++pp) {
        int c = rr + pp * 8;
        d[(size_t)(c0 + c) * R + r0 + cc] = f2bf(t[cc][c]);
    }
}

// ---------------- expert GEMMs: counted-vmcnt 3-buffer pipeline ----------------
// ROUND-9 VERIFIED CONFIG (best: 425 us) + XCD swizzle only.
// gemm1: 128x256, 512 threads = 8 waves (2M x 4N), 64x64/wave, vmcnt(3).
// gemm2: 128x128, 512 threads, 49 KB LDS -> 3 blk/CU, vmcnt(2).
// Round-10 lesson: 64x128 wave-tile at 256 threads halves waves/CU -> latency
// exposed, regressed. Keep 512-thread 64x64 config; attack A-refetch via XCD
// swizzle instead.

__global__ __launch_bounds__(512) void gemm1_kernel(
    const short* __restrict__ xbf, const short* __restrict__ w1t,
    const float* __restrict__ b1, const int* __restrict__ offs,
    const int* __restrict__ tile_e, const int* __restrict__ tile_m0,
    const int* __restrict__ list_tok, short* __restrict__ hbuf,
    int h0, int hlen, int t0, int tc)
{
    int ty, xn;
    xcd_decode((int)blockIdx.x, hlen / GBN, tc, ty, xn);
    int tb = t0 + ty;
    if (tb >= offs[17]) return;
    int e = tile_e[tb], m0 = tile_m0[tb];
    int rows = offs[e + 1] - m0; if (rows > GBM) rows = GBM;
    int n0 = xn * GBN;
    int tid = threadIdx.x, l = tid & 63, w = tid >> 6;

    __shared__ __align__(16) short As[3][GBM * BK];   // 3 x 8 KiB
    __shared__ __align__(16) short Bs[3][GBN * BK];   // 3 x 16 KiB
    __shared__ int ts[GBM];
    if (tid < GBM) ts[tid] = list_tok[m0 + (tid < rows ? tid : rows - 1)];
    __syncthreads();

    int arow = w * 16 + (l >> 2);
    int aslot = (l & 3) ^ ((arow >> 1) & 3);
    const short* gA = xbf + (size_t)ts[arow] * DDIM + aslot * 8;
    int brow0 = (w * 2 + 0) * 16 + (l >> 2);
    int brow1 = (w * 2 + 1) * 16 + (l >> 2);
    int bs0 = (l & 3) ^ ((brow0 >> 1) & 3);
    int bs1 = (l & 3) ^ ((brow1 >> 1) & 3);
    const short* gB0 = w1t + ((size_t)e * HDIM + (size_t)(h0 + n0 + brow0)) * DDIM + bs0 * 8;
    const short* gB1 = w1t + ((size_t)e * HDIM + (size_t)(h0 + n0 + brow1)) * DDIM + bs1 * 8;

    int l15 = l & 15, kq = l >> 4;
    int aoff[4], boff[4];
#pragma unroll
    for (int mi = 0; mi < 4; ++mi) {
        int R = (w >> 2) * 64 + mi * 16 + l15;
        aoff[mi] = R * BK + ((kq ^ ((R >> 1) & 3)) * 8);
    }
#pragma unroll
    for (int ni = 0; ni < 4; ++ni) {
        int S = (w & 3) * 64 + ni * 16 + l15;
        boff[ni] = S * BK + ((kq ^ ((S >> 1) & 3)) * 8);
    }

    f32x4 vzero = {0.0f, 0.0f, 0.0f, 0.0f};
    f32x4 acc[4][4];
#pragma unroll
    for (int i = 0; i < 4; ++i)
#pragma unroll
        for (int j = 0; j < 4; ++j) acc[i][j] = vzero;

#define STAGE1(T, B) {                                            \
        gload16(gA  + (T) * BK, &As[B][w * 512]);                 \
        gload16(gB0 + (T) * BK, &Bs[B][(w * 2 + 0) * 512]);       \
        gload16(gB1 + (T) * BK, &Bs[B][(w * 2 + 1) * 512]); }

    const int nt = DDIM / BK;          // 16
    STAGE1(0, 0);
    STAGE1(1, 1);
    int cb = 0, sb = 2;
#pragma unroll 1
    for (int t = 0; t < nt; ++t) {
        if (t < nt - 1) asm volatile("s_waitcnt vmcnt(3)" ::: "memory");
        else            asm volatile("s_waitcnt vmcnt(0)" ::: "memory");
        __builtin_amdgcn_s_barrier();
        __builtin_amdgcn_sched_barrier(0);
        if (t + 2 < nt) STAGE1(t + 2, sb);
        const short* Ab = &As[cb][0];
        const short* Bb = &Bs[cb][0];
        short8 af[4], bv[4];
#pragma unroll
        for (int mi = 0; mi < 4; ++mi) af[mi] = *(const short8*)(Ab + aoff[mi]);
#pragma unroll
        for (int ni = 0; ni < 4; ++ni) bv[ni] = *(const short8*)(Bb + boff[ni]);
        __builtin_amdgcn_s_setprio(1);
#pragma unroll
        for (int mi = 0; mi < 4; ++mi)
#pragma unroll
            for (int ni = 0; ni < 4; ++ni)
                acc[mi][ni] = __builtin_amdgcn_mfma_f32_16x16x32_bf16(
                    af[mi], bv[ni], acc[mi][ni], 0, 0, 0);
        __builtin_amdgcn_s_setprio(0);
        cb = (cb == 2) ? 0 : cb + 1;
        sb = (sb == 2) ? 0 : sb + 1;
    }
#undef STAGE1

    int crow = (w >> 2) * 64 + (kq << 2);
    int ccol = (w & 3) * 64 + l15;
#pragma unroll
    for (int mi = 0; mi < 4; ++mi) {
#pragma unroll
        for (int ni = 0; ni < 4; ++ni) {
            int col = ccol + ni * 16;
            float bias = b1[e * HDIM + h0 + n0 + col];
#pragma unroll
            for (int j = 0; j < 4; ++j) {
                int row = crow + mi * 16 + j;
                if (row < rows) {
                    float v = acc[mi][ni][j] + bias;
                    hbuf[(size_t)(m0 + row) * hlen + (n0 + col)] = f2bf(geluf(v));
                }
            }
        }
    }
}

__global__ __launch_bounds__(512) void gemm2_kernel(
    const short* __restrict__ hbuf, const short* __restrict__ w2t,
    const float* __restrict__ b2, const int* __restrict__ offs,
    const int* __restrict__ tile_e, const int* __restrict__ tile_m0,
    const int* __restrict__ list_tok, const float* __restrict__ list_w,
    short* __restrict__ ybuf, float* __restrict__ out,
    int h0, int hlen, int mode, int t0, int tc)
{
    int ty, xn;
    xcd_decode((int)blockIdx.x, DDIM / GBN2, tc, ty, xn);
    int tb = t0 + ty;
    if (tb >= offs[17]) return;
    int e = tile_e[tb], m0 = tile_m0[tb];
    int rows = offs[e + 1] - m0; if (rows > GBM) rows = GBM;
    int n0 = xn * GBN2;                  // output d coordinate
    int tid = threadIdx.x, l = tid & 63, w = tid >> 6;

    __shared__ __align__(16) short As[3][GBM * BK];    // 3 x 8 KiB
    __shared__ __align__(16) short Bs[3][GBN2 * BK];   // 3 x 8 KiB
    __shared__ int ts[GBM];
    __shared__ float lw[GBM];
    if (tid < GBM) {
        int idx = m0 + (tid < rows ? tid : rows - 1);
        ts[tid] = list_tok[idx];
        lw[tid] = list_w[idx];
    }
    __syncthreads();

    // staging: A rows w*16.., B rows (d) w*16..; 1 gload16 each per wave
    int arow = w * 16 + (l >> 2);
    int aslot = (l & 3) ^ ((arow >> 1) & 3);
    int aslotg = m0 + arow; if (aslotg >= NSLOT) aslotg = NSLOT - 1;
    const short* gA = hbuf + (size_t)aslotg * hlen + aslot * 8;
    int brow = w * 16 + (l >> 2);
    int bslot = (l & 3) ^ ((brow >> 1) & 3);
    const short* gB = w2t + ((size_t)e * DDIM + (size_t)(n0 + brow)) * HDIM + h0 + bslot * 8;

    // wave-grid 2M x 4N: wave-tile 64 x 32
    int l15 = l & 15, kq = l >> 4;
    int aoff[4], boff[2];
#pragma unroll
    for (int mi = 0; mi < 4; ++mi) {
        int R = (w >> 2) * 64 + mi * 16 + l15;
        aoff[mi] = R * BK + ((kq ^ ((R >> 1) & 3)) * 8);
    }
#pragma unroll
    for (int ni = 0; ni < 2; ++ni) {
        int S = (w & 3) * 32 + ni * 16 + l15;
        boff[ni] = S * BK + ((kq ^ ((S >> 1) & 3)) * 8);
    }

    f32x4 vzero = {0.0f, 0.0f, 0.0f, 0.0f};
    f32x4 acc[4][2];
#pragma unroll
    for (int i = 0; i < 4; ++i)
#pragma unroll
        for (int j = 0; j < 2; ++j) acc[i][j] = vzero;

#define STAGE2(T, B) {                                            \
        gload16(gA + (T) * BK, &As[B][w * 512]);                  \
        gload16(gB + (T) * BK, &Bs[B][w * 512]); }

    const int nt = hlen / BK;          // 64 at hlen=2048
    STAGE2(0, 0);
    STAGE2(1, 1);
    int cb = 0, sb = 2;
#pragma unroll 1
    for (int t = 0; t < nt; ++t) {
        if (t < nt - 1) asm volatile("s_waitcnt vmcnt(2)" ::: "memory");
        else            asm volatile("s_waitcnt vmcnt(0)" ::: "memory");
        __builtin_amdgcn_s_barrier();
        __builtin_amdgcn_sched_barrier(0);
        if (t + 2 < nt) STAGE2(t + 2, sb);
        const short* Ab = &As[cb][0];
        const short* Bb = &Bs[cb][0];
        short8 af[4], bv[2];
#pragma unroll
        for (int mi = 0; mi < 4; ++mi) af[mi] = *(const short8*)(Ab + aoff[mi]);
#pragma unroll
        for (int ni = 0; ni < 2; ++ni) bv[ni] = *(const short8*)(Bb + boff[ni]);
        __builtin_amdgcn_s_setprio(1);
#pragma unroll
        for (int mi = 0; mi < 4; ++mi)
#pragma unroll
            for (int ni = 0; ni < 2; ++ni)
                acc[mi][ni] = __builtin_amdgcn_mfma_f32_16x16x32_bf16(
                    af[mi], bv[ni], acc[mi][ni], 0, 0, 0);
        __builtin_amdgcn_s_setprio(0);
        cb = (cb == 2) ? 0 : cb + 1;
        sb = (sb == 2) ? 0 : sb + 1;
    }
#undef STAGE2

    int crow = (w >> 2) * 64 + (kq << 2);
    int ccol = (w & 3) * 32 + l15;
#pragma unroll
    for (int mi = 0; mi < 4; ++mi) {
#pragma unroll
        for (int ni = 0; ni < 2; ++ni) {
            int col = ccol + ni * 16;
            float bias = (h0 == 0) ? b2[e * DDIM + n0 + col] : 0.0f;
#pragma unroll
            for (int j = 0; j < 4; ++j) {
                int row = crow + mi * 16 + j;
                if (row < rows) {
                    float v = acc[mi][ni][j] + bias;
                    if (mode == 0)   // full-K path: single bf16 write
                        ybuf[(size_t)(m0 + row) * DDIM + n0 + col] = f2bf(v);
                    else
                        atomicAdd(&out[(size_t)ts[row] * DDIM + n0 + col], lw[row] * v);
                }
            }
        }
    }
}

// out[t] = w0*ybuf[pos0] + w1*ybuf[pos1]  (ybuf bf16, 8 cols/thread)
__global__ __launch_bounds__(256) void combine_kernel(
    const short* __restrict__ ybuf, const int* __restrict__ pos_tk,
    const float* __restrict__ tok_w, float* __restrict__ out)
{
    int i = blockIdx.x * 256 + threadIdx.x;   // over T_TOK * 64 units
    int t = i >> 6, c = (i & 63) * 8;
    float w0 = tok_w[2 * t], w1 = tok_w[2 * t + 1];
    int p0 = pos_tk[2 * t], p1 = pos_tk[2 * t + 1];
    short8 a = *(const short8*)(ybuf + (size_t)p0 * DDIM + c);
    short8 b = *(const short8*)(ybuf + (size_t)p1 * DDIM + c);
    float4 o0, o1;
    float* op = (float*)&o0;
#pragma unroll
    for (int j = 0; j < 4; ++j) op[j] = w0 * bf2f(a[j]) + w1 * bf2f(b[j]);
    float* op1 = (float*)&o1;
#pragma unroll
    for (int j = 0; j < 4; ++j) op1[j] = w0 * bf2f(a[4 + j]) + w1 * bf2f(b[4 + j]);
    float4* ob = (float4*)(out + (size_t)t * DDIM + c);
    ob[0] = o0;
    ob[1] = o1;
}

// ---------------- launch ----------------

extern "C" void kernel_launch(void* const* d_in, const int* in_sizes, int n_in,
                              void* d_out, int out_size, void* d_ws, size_t ws_size,
                              hipStream_t stream)
{
    const float* x  = (const float*)d_in[0];
    const float* wg = (const float*)d_in[1];
    const float* bg = (const float*)d_in[2];
    const float* w1 = (const float*)d_in[3];
    const float* b1 = (const float*)d_in[4];
    const float* w2 = (const float*)d_in[5];
    const float* b2 = (const float*)d_in[6];
    float* out = (float*)d_out;

    char* p = (char*)d_ws;
    int* offs     = (int*)(p + 128);            // 32 ints
    int* tile_e   = (int*)(p + 256);            // 512 ints
    int* tile_m0  = (int*)(p + 2304);           // 512 ints
    int* bhist    = (int*)(p + 8192);           // 8 KiB
    int* bbase    = (int*)(p + 16384);          // 8 KiB
    int* tok_e    = (int*)(p + 32768);          // 128 KiB
    float* tok_w  = (float*)(p + 32768 + 131072);
    int* list_tok = (int*)(p + 32768 + 262144);
    float* list_w = (float*)(p + 32768 + 393216);
    int* pos_tk   = (int*)(p + 32768 + 524288);
    short* xbf    = (short*)(p + 32768 + 655360);             // 16 MiB
    short* w1t    = xbf + (size_t)T_TOK * DDIM;               // 32 MiB
    short* w2t    = w1t + (size_t)NEXP * DDIM * HDIM;         // 32 MiB
    char* after   = (char*)(w2t + (size_t)NEXP * DDIM * HDIM);
    size_t fixed  = (size_t)(after - p);

    // mode 0: full-K gemm2 + bf16 ybuf + combine (needs hbuf 134 MB + ybuf 33.5 MB)
    // mode 1 fallback: h-chunked gemm2 with atomic out accumulate.
    int mode, hlen = HDIM;
    if (fixed + (size_t)NSLOT * DDIM * 2 + (size_t)NSLOT * HDIM * 2 <= ws_size) {
        mode = 0;
    } else {
        mode = 1;
        hlen = 0;
        for (int hl = HDIM; hl >= 128; hl >>= 1)
            if (fixed + (size_t)NSLOT * hl * 2 <= ws_size) { hlen = hl; break; }
    }
    short* ybuf = (short*)after;
    short* hbuf = (mode == 0) ? (short*)(after + (size_t)NSLOT * DDIM * 2) : (short*)after;

    if (!hlen) { hipMemsetAsync(d_out, 0, (size_t)out_size * sizeof(float), stream); return; }
    if (mode == 1) hipMemsetAsync(d_out, 0, (size_t)out_size * sizeof(float), stream);

    gate_kernel<<<T_TOK / 4, 256, 0, stream>>>(x, wg, bg, tok_e, tok_w);
    hist_kernel<<<NHB, 256, 0, stream>>>(tok_e, bhist);
    scan_kernel<<<1, 64, 0, stream>>>(bhist, offs, bbase, tile_e, tile_m0);
    scatter_kernel<<<NHB, 256, 0, stream>>>(tok_e, tok_w, bbase, list_tok, list_w, pos_tk);
    cvt_bf16_kernel<<<2048, 256, 0, stream>>>(x, xbf, T_TOK * DDIM / 4);
    wtrans_kernel<<<dim3(HDIM / 32, DDIM / 32, NEXP), 256, 0, stream>>>(w1, w1t, DDIM, HDIM);
    wtrans_kernel<<<dim3(DDIM / 32, HDIM / 32, NEXP), 256, 0, stream>>>(w2, w2t, HDIM, DDIM);

    // m-tile slices: gemm2(slice) consumes hbuf(slice) while it is L3-hot.
    // 1-D grids + XCD-aware decode: a tile's n-chunk blocks share one XCD.
    for (int h0 = 0; h0 < HDIM; h0 += hlen) {
        for (int t0 = 0; t0 < MAXTILE; t0 += TSLICE) {
            int tc = MAXTILE - t0; if (tc > TSLICE) tc = TSLICE;
            gemm1_kernel<<<(hlen / GBN) * tc, 512, 0, stream>>>(
                xbf, w1t, b1, offs, tile_e, tile_m0, list_tok, hbuf, h0, hlen, t0, tc);
            gemm2_kernel<<<(DDIM / GBN2) * tc, 512, 0, stream>>>(
                hbuf, w2t, b2, offs, tile_e, tile_m0, list_tok, list_w,
                ybuf, out, h0, hlen, mode, t0, tc);
        }
    }
    if (mode == 0)
        combine_kernel<<<T_TOK * 64 / 256, 256, 0, stream>>>(ybuf, pos_tk, tok_w, out);
}

// Round 12
// 397.861 us; speedup vs baseline: 1.2583x; 1.0062x over previous
//
#include <hip/hip_runtime.h>
#include <hip/hip_bf16.h>

// MoE: B=4,S=4096,D=512,E=16,H=2048,top-2. T=16384 tokens, 32768 slots.
#define T_TOK 16384
#define DDIM  512
#define NEXP  16
#define HDIM  2048
#define NSLOT (T_TOK * 2)
#define NHB   128         // histogram blocks: NSLOT / 256

#define GBM 128           // gemm tile M (matches tile table)
#define GBN 256           // gemm1 tile N
#define GBN2 128          // gemm2 tile N
#define BK  32            // gemm K-step
#define MAXTILE 272       // max m-tiles: 32768/128 + 16
#define TSLICE  136       // m-tile slice: hbuf slice ~67 MB stays L3-resident

typedef __attribute__((ext_vector_type(8))) short short8;   // 8 x bf16
typedef __attribute__((ext_vector_type(4))) short short4v;
typedef __attribute__((ext_vector_type(4))) float f32x4;

__device__ inline short f2bf(float f) {
    __hip_bfloat16 h = __float2bfloat16(f);
    return *reinterpret_cast<short*>(&h);
}
__device__ inline float bf2f(short s) {
    unsigned u = ((unsigned)(unsigned short)s) << 16;
    union { unsigned u; float f; } c; c.u = u; return c.f;
}
// A&S 7.1.26 erf: |abs err| < 1.5e-7 (<< bf16 rounding of hbuf). ~14 VALU ops.
__device__ inline float erf_fast(float x) {
    float ax = fabsf(x);
    float t = 1.0f / fmaf(0.3275911f, ax, 1.0f);
    float p = fmaf(fmaf(fmaf(fmaf(1.061405429f, t, -1.453152027f), t,
                  1.421413741f), t, -0.284496736f), t, 0.254829592f) * t;
    float r = 1.0f - p * __expf(-ax * ax);
    return copysignf(r, x);
}
__device__ inline float geluf(float v) {   // exact-form gelu via fast erf
    return 0.5f * v * (1.0f + erf_fast(v * 0.70710678118654752440f));
}
// async global->LDS, 16B per lane. LDS dest = WAVE-UNIFORM base + lane*16.
__device__ inline void gload16(const void* g, void* l) {
    __builtin_amdgcn_global_load_lds(
        (const __attribute__((address_space(1))) void*)g,
        (__attribute__((address_space(3))) void*)l, 16, 0, 0);
}
// XCD-aware decode of a 1-D grid (lin over nx*tc blocks) into (tile y, chunk xn).
// HW assigns XCD = linear_wg_id % 8; equal lin%8 for a tile's n-chunks keeps
// them on ONE XCD -> A-tile L2-resident (round-11: FETCH 74->37 MB, -25 us).
__device__ inline void xcd_decode(int lin, int nx, int tc, int& y, int& xn) {
    if ((tc & 7) == 0) {
        int tpx = tc >> 3;
        int k = lin & 7, j = lin >> 3;
        y = k * tpx + j % tpx;
        xn = j / tpx;
    } else {
        xn = lin % nx;
        y = lin / nx;
    }
}

// ---------------- routing ----------------
// wave-per-token gate: lane (g,q) = (d-quarter, expert). fp64 (tie-robust).
__global__ __launch_bounds__(256) void gate_kernel(
    const float* __restrict__ x, const float* __restrict__ wg,
    const float* __restrict__ bg, int* __restrict__ tok_e,
    float* __restrict__ tok_w)
{
    int wv = threadIdx.x >> 6, lane = threadIdx.x & 63;
    int t = blockIdx.x * 4 + wv;
    int g = lane >> 4, q = lane & 15;
    const float* xr = x + (size_t)t * DDIM + g * 128;
    const float* wr = wg + (size_t)g * 128 * NEXP + q;
    double a0 = 0, a1 = 0, a2 = 0, a3 = 0;
#pragma unroll
    for (int c = 0; c < 8; ++c) {
        float4 v0 = ((const float4*)xr)[c * 4 + 0];
        float4 v1 = ((const float4*)xr)[c * 4 + 1];
        float4 v2 = ((const float4*)xr)[c * 4 + 2];
        float4 v3 = ((const float4*)xr)[c * 4 + 3];
        const float* wp = wr + c * 16 * NEXP;
        a0 += (double)v0.x * (double)wp[0 * NEXP];
        a1 += (double)v0.y * (double)wp[1 * NEXP];
        a2 += (double)v0.z * (double)wp[2 * NEXP];
        a3 += (double)v0.w * (double)wp[3 * NEXP];
        a0 += (double)v1.x * (double)wp[4 * NEXP];
        a1 += (double)v1.y * (double)wp[5 * NEXP];
        a2 += (double)v1.z * (double)wp[6 * NEXP];
        a3 += (double)v1.w * (double)wp[7 * NEXP];
        a0 += (double)v2.x * (double)wp[8 * NEXP];
        a1 += (double)v2.y * (double)wp[9 * NEXP];
        a2 += (double)v2.z * (double)wp[10 * NEXP];
        a3 += (double)v2.w * (double)wp[11 * NEXP];
        a0 += (double)v3.x * (double)wp[12 * NEXP];
        a1 += (double)v3.y * (double)wp[13 * NEXP];
        a2 += (double)v3.z * (double)wp[14 * NEXP];
        a3 += (double)v3.w * (double)wp[15 * NEXP];
    }
    double a = ((a0 + a1) + (a2 + a3));
    a += __shfl_xor(a, 16, 64);
    a += __shfl_xor(a, 32, 64);
    a += (double)bg[q];
    double v0 = a; int i0 = q;
#pragma unroll
    for (int s = 1; s < 16; s <<= 1) {
        double ov = __shfl_xor(v0, s, 64);
        int oi = __shfl_xor(i0, s, 64);
        if (ov > v0 || (ov == v0 && oi < i0)) { v0 = ov; i0 = oi; }
    }
    double m2 = (q == i0) ? -1e300 : a;
    double v1 = m2; int i1 = q;
#pragma unroll
    for (int s = 1; s < 16; s <<= 1) {
        double ov = __shfl_xor(v1, s, 64);
        int oi = __shfl_xor(i1, s, 64);
        if (ov > v1 || (ov == v1 && oi < i1)) { v1 = ov; i1 = oi; }
    }
    if (lane == 0) {
        float ex = expf((float)(v1 - v0));      // <= 1
        float w0 = 1.0f / (1.0f + ex);
        tok_e[2 * t] = i0; tok_e[2 * t + 1] = i1;
        tok_w[2 * t] = w0; tok_w[2 * t + 1] = ex * w0;
    }
}

// per-block expert histogram (LDS atomics only)
__global__ __launch_bounds__(256) void hist_kernel(
    const int* __restrict__ tok_e, int* __restrict__ bhist)
{
    __shared__ int h[NEXP];
    if (threadIdx.x < NEXP) h[threadIdx.x] = 0;
    __syncthreads();
    atomicAdd(&h[tok_e[blockIdx.x * 256 + threadIdx.x]], 1);
    __syncthreads();
    if (threadIdx.x < NEXP) bhist[blockIdx.x * NEXP + threadIdx.x] = h[threadIdx.x];
}

// offs[0..16] = exclusive scan; offs[17] = ntiles; bbase[b][e] = scatter base.
__global__ void scan_kernel(const int* __restrict__ bhist, int* __restrict__ offs,
                            int* __restrict__ bbase, int* __restrict__ tile_e,
                            int* __restrict__ tile_m0)
{
    int tid = threadIdx.x;
    __shared__ int tot[NEXP];
    if (tid < NEXP) {
        int s = 0;
        for (int b = 0; b < NHB; ++b) s += bhist[b * NEXP + tid];
        tot[tid] = s;
    }
    __syncthreads();
    if (tid == 0) {
        int run = 0;
        for (int e = 0; e < NEXP; ++e) { offs[e] = run; run += tot[e]; }
        offs[NEXP] = run;   // == NSLOT
        int nt = 0;
        for (int e = 0; e < NEXP; ++e)
            for (int m = offs[e]; m < offs[e + 1]; m += GBM) {
                tile_e[nt] = e; tile_m0[nt] = m; ++nt;
            }
        offs[17] = nt;
    }
    __syncthreads();
    if (tid < NEXP) {
        int run = offs[tid];
        for (int b = 0; b < NHB; ++b) {
            bbase[b * NEXP + tid] = run;
            run += bhist[b * NEXP + tid];
        }
    }
}

// local rank via LDS atomic + precomputed block base
__global__ __launch_bounds__(256) void scatter_kernel(
    const int* __restrict__ tok_e, const float* __restrict__ tok_w,
    const int* __restrict__ bbase, int* __restrict__ list_tok,
    float* __restrict__ list_w, int* __restrict__ pos_tk)
{
    __shared__ int h[NEXP];
    if (threadIdx.x < NEXP) h[threadIdx.x] = 0;
    __syncthreads();
    int s = blockIdx.x * 256 + threadIdx.x;
    int e = tok_e[s];
    int r = atomicAdd(&h[e], 1);
    int pos = bbase[blockIdx.x * NEXP + e] + r;
    list_tok[pos] = s >> 1;
    list_w[pos] = tok_w[s];
    pos_tk[s] = pos;
}

// ---------------- pre-conversion ----------------

__global__ void cvt_bf16_kernel(const float* __restrict__ src, short* __restrict__ dst, int n4)
{
    int i = blockIdx.x * blockDim.x + threadIdx.x;
    int stride = gridDim.x * blockDim.x;
    for (; i < n4; i += stride) {
        float4 v = ((const float4*)src)[i];
        short4v o;
        o[0] = f2bf(v.x); o[1] = f2bf(v.y); o[2] = f2bf(v.z); o[3] = f2bf(v.w);
        ((short4v*)dst)[i] = o;
    }
}

// transpose one [R][C] fp32 matrix per blockIdx.z into [C][R] bf16
__global__ void wtrans_kernel(const float* __restrict__ src, short* __restrict__ dst, int R, int C)
{
    __shared__ float t[32][33];
    int c0 = blockIdx.x * 32, r0 = blockIdx.y * 32;
    const float* s = src + (size_t)blockIdx.z * R * C;
    short* d = dst + (size_t)blockIdx.z * R * C;
    int cc = threadIdx.x & 31, rr = threadIdx.x >> 5;
#pragma unroll
    for (int pp = 0; pp < 4; ++pp)
        t[rr + pp * 8][cc] = s[(size_t)(r0 + rr + pp * 8) * C + c0 + cc];
    __syncthreads();
#pragma unroll
    for (int pp = 0; pp < 4; ++pp) {
        int c = rr + pp * 8;
        d[(size_t)(c0 + c) * R + r0 + cc] = f2bf(t[cc][c]);
    }
}

// ---------------- expert GEMMs: 2-buf prefetch-early pipeline ----------------
// Round-12 change: 3-buf counted-vmcnt (74 KB, 2 blk/CU, Occ 29%) -> 2-buf
// T3-minimum schedule (STAGE(t+1) issued BEFORE compute(t); vmcnt(0)+barrier
// AFTER compute - loads fly across the whole MFMA section). LDS 49/33 KB ->
// gemm1 3 blk/CU, gemm2 4 blk/CU: occupancy is the round-11 binder.
// T2 swizzle both-sides + XCD swizzle retained.

__global__ __launch_bounds__(512) void gemm1_kernel(
    const short* __restrict__ xbf, const short* __restrict__ w1t,
    const float* __restrict__ b1, const int* __restrict__ offs,
    const int* __restrict__ tile_e, const int* __restrict__ tile_m0,
    const int* __restrict__ list_tok, short* __restrict__ hbuf,
    int h0, int hlen, int t0, int tc)
{
    int ty, xn;
    xcd_decode((int)blockIdx.x, hlen / GBN, tc, ty, xn);
    int tb = t0 + ty;
    if (tb >= offs[17]) return;
    int e = tile_e[tb], m0 = tile_m0[tb];
    int rows = offs[e + 1] - m0; if (rows > GBM) rows = GBM;
    int n0 = xn * GBN;
    int tid = threadIdx.x, l = tid & 63, w = tid >> 6;

    __shared__ __align__(16) short As[2][GBM * BK];   // 2 x 8 KiB
    __shared__ __align__(16) short Bs[2][GBN * BK];   // 2 x 16 KiB
    __shared__ int ts[GBM];
    if (tid < GBM) ts[tid] = list_tok[m0 + (tid < rows ? tid : rows - 1)];
    __syncthreads();

    int arow = w * 16 + (l >> 2);
    int aslot = (l & 3) ^ ((arow >> 1) & 3);
    const short* gA = xbf + (size_t)ts[arow] * DDIM + aslot * 8;
    int brow0 = (w * 2 + 0) * 16 + (l >> 2);
    int brow1 = (w * 2 + 1) * 16 + (l >> 2);
    int bs0 = (l & 3) ^ ((brow0 >> 1) & 3);
    int bs1 = (l & 3) ^ ((brow1 >> 1) & 3);
    const short* gB0 = w1t + ((size_t)e * HDIM + (size_t)(h0 + n0 + brow0)) * DDIM + bs0 * 8;
    const short* gB1 = w1t + ((size_t)e * HDIM + (size_t)(h0 + n0 + brow1)) * DDIM + bs1 * 8;

    int l15 = l & 15, kq = l >> 4;
    int aoff[4], boff[4];
#pragma unroll
    for (int mi = 0; mi < 4; ++mi) {
        int R = (w >> 2) * 64 + mi * 16 + l15;
        aoff[mi] = R * BK + ((kq ^ ((R >> 1) & 3)) * 8);
    }
#pragma unroll
    for (int ni = 0; ni < 4; ++ni) {
        int S = (w & 3) * 64 + ni * 16 + l15;
        boff[ni] = S * BK + ((kq ^ ((S >> 1) & 3)) * 8);
    }

    f32x4 vzero = {0.0f, 0.0f, 0.0f, 0.0f};
    f32x4 acc[4][4];
#pragma unroll
    for (int i = 0; i < 4; ++i)
#pragma unroll
        for (int j = 0; j < 4; ++j) acc[i][j] = vzero;

#define STAGE1(T, B) {                                            \
        gload16(gA  + (T) * BK, &As[B][w * 512]);                 \
        gload16(gB0 + (T) * BK, &Bs[B][(w * 2 + 0) * 512]);       \
        gload16(gB1 + (T) * BK, &Bs[B][(w * 2 + 1) * 512]); }

    const int nt = DDIM / BK;          // 16
    STAGE1(0, 0);
    asm volatile("s_waitcnt vmcnt(0)" ::: "memory");
    __builtin_amdgcn_s_barrier();
#pragma unroll 1
    for (int t = 0; t < nt; ++t) {
        int cur = t & 1;
        if (t + 1 < nt) STAGE1(t + 1, cur ^ 1);
        __builtin_amdgcn_sched_barrier(0);
        const short* Ab = &As[cur][0];
        const short* Bb = &Bs[cur][0];
        short8 af[4], bv[4];
#pragma unroll
        for (int mi = 0; mi < 4; ++mi) af[mi] = *(const short8*)(Ab + aoff[mi]);
#pragma unroll
        for (int ni = 0; ni < 4; ++ni) bv[ni] = *(const short8*)(Bb + boff[ni]);
        __builtin_amdgcn_s_setprio(1);
#pragma unroll
        for (int mi = 0; mi < 4; ++mi)
#pragma unroll
            for (int ni = 0; ni < 4; ++ni)
                acc[mi][ni] = __builtin_amdgcn_mfma_f32_16x16x32_bf16(
                    af[mi], bv[ni], acc[mi][ni], 0, 0, 0);
        __builtin_amdgcn_s_setprio(0);
        if (t + 1 < nt) {
            asm volatile("s_waitcnt vmcnt(0)" ::: "memory");
            __builtin_amdgcn_s_barrier();
        }
    }
#undef STAGE1

    int crow = (w >> 2) * 64 + (kq << 2);
    int ccol = (w & 3) * 64 + l15;
#pragma unroll
    for (int mi = 0; mi < 4; ++mi) {
#pragma unroll
        for (int ni = 0; ni < 4; ++ni) {
            int col = ccol + ni * 16;
            float bias = b1[e * HDIM + h0 + n0 + col];
#pragma unroll
            for (int j = 0; j < 4; ++j) {
                int row = crow + mi * 16 + j;
                if (row < rows) {
                    float v = acc[mi][ni][j] + bias;
                    hbuf[(size_t)(m0 + row) * hlen + (n0 + col)] = f2bf(geluf(v));
                }
            }
        }
    }
}

__global__ __launch_bounds__(512) void gemm2_kernel(
    const short* __restrict__ hbuf, const short* __restrict__ w2t,
    const float* __restrict__ b2, const int* __restrict__ offs,
    const int* __restrict__ tile_e, const int* __restrict__ tile_m0,
    const int* __restrict__ list_tok, const float* __restrict__ list_w,
    short* __restrict__ ybuf, float* __restrict__ out,
    int h0, int hlen, int mode, int t0, int tc)
{
    int ty, xn;
    xcd_decode((int)blockIdx.x, DDIM / GBN2, tc, ty, xn);
    int tb = t0 + ty;
    if (tb >= offs[17]) return;
    int e = tile_e[tb], m0 = tile_m0[tb];
    int rows = offs[e + 1] - m0; if (rows > GBM) rows = GBM;
    int n0 = xn * GBN2;                  // output d coordinate
    int tid = threadIdx.x, l = tid & 63, w = tid >> 6;

    __shared__ __align__(16) short As[2][GBM * BK];    // 2 x 8 KiB
    __shared__ __align__(16) short Bs[2][GBN2 * BK];   // 2 x 8 KiB
    __shared__ int ts[GBM];
    __shared__ float lw[GBM];
    if (tid < GBM) {
        int idx = m0 + (tid < rows ? tid : rows - 1);
        ts[tid] = list_tok[idx];
        lw[tid] = list_w[idx];
    }
    __syncthreads();

    // staging: A rows w*16.., B rows (d) w*16..; 1 gload16 each per wave
    int arow = w * 16 + (l >> 2);
    int aslot = (l & 3) ^ ((arow >> 1) & 3);
    int aslotg = m0 + arow; if (aslotg >= NSLOT) aslotg = NSLOT - 1;
    const short* gA = hbuf + (size_t)aslotg * hlen + aslot * 8;
    int brow = w * 16 + (l >> 2);
    int bslot = (l & 3) ^ ((brow >> 1) & 3);
    const short* gB = w2t + ((size_t)e * DDIM + (size_t)(n0 + brow)) * HDIM + h0 + bslot * 8;

    // wave-grid 2M x 4N: wave-tile 64 x 32
    int l15 = l & 15, kq = l >> 4;
    int aoff[4], boff[2];
#pragma unroll
    for (int mi = 0; mi < 4; ++mi) {
        int R = (w >> 2) * 64 + mi * 16 + l15;
        aoff[mi] = R * BK + ((kq ^ ((R >> 1) & 3)) * 8);
    }
#pragma unroll
    for (int ni = 0; ni < 2; ++ni) {
        int S = (w & 3) * 32 + ni * 16 + l15;
        boff[ni] = S * BK + ((kq ^ ((S >> 1) & 3)) * 8);
    }

    f32x4 vzero = {0.0f, 0.0f, 0.0f, 0.0f};
    f32x4 acc[4][2];
#pragma unroll
    for (int i = 0; i < 4; ++i)
#pragma unroll
        for (int j = 0; j < 2; ++j) acc[i][j] = vzero;

#define STAGE2(T, B) {                                            \
        gload16(gA + (T) * BK, &As[B][w * 512]);                  \
        gload16(gB + (T) * BK, &Bs[B][w * 512]); }

    const int nt = hlen / BK;          // 64 at hlen=2048
    STAGE2(0, 0);
    asm volatile("s_waitcnt vmcnt(0)" ::: "memory");
    __builtin_amdgcn_s_barrier();
#pragma unroll 1
    for (int t = 0; t < nt; ++t) {
        int cur = t & 1;
        if (t + 1 < nt) STAGE2(t + 1, cur ^ 1);
        __builtin_amdgcn_sched_barrier(0);
        const short* Ab = &As[cur][0];
        const short* Bb = &Bs[cur][0];
        short8 af[4], bv[2];
#pragma unroll
        for (int mi = 0; mi < 4; ++mi) af[mi] = *(const short8*)(Ab + aoff[mi]);
#pragma unroll
        for (int ni = 0; ni < 2; ++ni) bv[ni] = *(const short8*)(Bb + boff[ni]);
        __builtin_amdgcn_s_setprio(1);
#pragma unroll
        for (int mi = 0; mi < 4; ++mi)
#pragma unroll
            for (int ni = 0; ni < 2; ++ni)
                acc[mi][ni] = __builtin_amdgcn_mfma_f32_16x16x32_bf16(
                    af[mi], bv[ni], acc[mi][ni], 0, 0, 0);
        __builtin_amdgcn_s_setprio(0);
        if (t + 1 < nt) {
            asm volatile("s_waitcnt vmcnt(0)" ::: "memory");
            __builtin_amdgcn_s_barrier();
        }
    }
#undef STAGE2

    int crow = (w >> 2) * 64 + (kq << 2);
    int ccol = (w & 3) * 32 + l15;
#pragma unroll
    for (int mi = 0; mi < 4; ++mi) {
#pragma unroll
        for (int ni = 0; ni < 2; ++ni) {
            int col = ccol + ni * 16;
            float bias = (h0 == 0) ? b2[e * DDIM + n0 + col] : 0.0f;
#pragma unroll
            for (int j = 0; j < 4; ++j) {
                int row = crow + mi * 16 + j;
                if (row < rows) {
                    float v = acc[mi][ni][j] + bias;
                    if (mode == 0)   // full-K path: single bf16 write
                        ybuf[(size_t)(m0 + row) * DDIM + n0 + col] = f2bf(v);
                    else
                        atomicAdd(&out[(size_t)ts[row] * DDIM + n0 + col], lw[row] * v);
                }
            }
        }
    }
}

// out[t] = w0*ybuf[pos0] + w1*ybuf[pos1]  (ybuf bf16, 8 cols/thread)
__global__ __launch_bounds__(256) void combine_kernel(
    const short* __restrict__ ybuf, const int* __restrict__ pos_tk,
    const float* __restrict__ tok_w, float* __restrict__ out)
{
    int i = blockIdx.x * 256 + threadIdx.x;   // over T_TOK * 64 units
    int t = i >> 6, c = (i & 63) * 8;
    float w0 = tok_w[2 * t], w1 = tok_w[2 * t + 1];
    int p0 = pos_tk[2 * t], p1 = pos_tk[2 * t + 1];
    short8 a = *(const short8*)(ybuf + (size_t)p0 * DDIM + c);
    short8 b = *(const short8*)(ybuf + (size_t)p1 * DDIM + c);
    float4 o0, o1;
    float* op = (float*)&o0;
#pragma unroll
    for (int j = 0; j < 4; ++j) op[j] = w0 * bf2f(a[j]) + w1 * bf2f(b[j]);
    float* op1 = (float*)&o1;
#pragma unroll
    for (int j = 0; j < 4; ++j) op1[j] = w0 * bf2f(a[4 + j]) + w1 * bf2f(b[4 + j]);
    float4* ob = (float4*)(out + (size_t)t * DDIM + c);
    ob[0] = o0;
    ob[1] = o1;
}

// ---------------- launch ----------------

extern "C" void kernel_launch(void* const* d_in, const int* in_sizes, int n_in,
                              void* d_out, int out_size, void* d_ws, size_t ws_size,
                              hipStream_t stream)
{
    const float* x  = (const float*)d_in[0];
    const float* wg = (const float*)d_in[1];
    const float* bg = (const float*)d_in[2];
    const float* w1 = (const float*)d_in[3];
    const float* b1 = (const float*)d_in[4];
    const float* w2 = (const float*)d_in[5];
    const float* b2 = (const float*)d_in[6];
    float* out = (float*)d_out;

    char* p = (char*)d_ws;
    int* offs     = (int*)(p + 128);            // 32 ints
    int* tile_e   = (int*)(p + 256);            // 512 ints
    int* tile_m0  = (int*)(p + 2304);           // 512 ints
    int* bhist    = (int*)(p + 8192);           // 8 KiB
    int* bbase    = (int*)(p + 16384);          // 8 KiB
    int* tok_e    = (int*)(p + 32768);          // 128 KiB
    float* tok_w  = (float*)(p + 32768 + 131072);
    int* list_tok = (int*)(p + 32768 + 262144);
    float* list_w = (float*)(p + 32768 + 393216);
    int* pos_tk   = (int*)(p + 32768 + 524288);
    short* xbf    = (short*)(p + 32768 + 655360);             // 16 MiB
    short* w1t    = xbf + (size_t)T_TOK * DDIM;               // 32 MiB
    short* w2t    = w1t + (size_t)NEXP * DDIM * HDIM;         // 32 MiB
    char* after   = (char*)(w2t + (size_t)NEXP * DDIM * HDIM);
    size_t fixed  = (size_t)(after - p);

    // mode 0: full-K gemm2 + bf16 ybuf + combine (needs hbuf 134 MB + ybuf 33.5 MB)
    // mode 1 fallback: h-chunked gemm2 with atomic out accumulate.
    int mode, hlen = HDIM;
    if (fixed + (size_t)NSLOT * DDIM * 2 + (size_t)NSLOT * HDIM * 2 <= ws_size) {
        mode = 0;
    } else {
        mode = 1;
        hlen = 0;
        for (int hl = HDIM; hl >= 128; hl >>= 1)
            if (fixed + (size_t)NSLOT * hl * 2 <= ws_size) { hlen = hl; break; }
    }
    short* ybuf = (short*)after;
    short* hbuf = (mode == 0) ? (short*)(after + (size_t)NSLOT * DDIM * 2) : (short*)after;

    if (!hlen) { hipMemsetAsync(d_out, 0, (size_t)out_size * sizeof(float), stream); return; }
    if (mode == 1) hipMemsetAsync(d_out, 0, (size_t)out_size * sizeof(float), stream);

    gate_kernel<<<T_TOK / 4, 256, 0, stream>>>(x, wg, bg, tok_e, tok_w);
    hist_kernel<<<NHB, 256, 0, stream>>>(tok_e, bhist);
    scan_kernel<<<1, 64, 0, stream>>>(bhist, offs, bbase, tile_e, tile_m0);
    scatter_kernel<<<NHB, 256, 0, stream>>>(tok_e, tok_w, bbase, list_tok, list_w, pos_tk);
    cvt_bf16_kernel<<<2048, 256, 0, stream>>>(x, xbf, T_TOK * DDIM / 4);
    wtrans_kernel<<<dim3(HDIM / 32, DDIM / 32, NEXP), 256, 0, stream>>>(w1, w1t, DDIM, HDIM);
    wtrans_kernel<<<dim3(DDIM / 32, HDIM / 32, NEXP), 256, 0, stream>>>(w2, w2t, HDIM, DDIM);

    // m-tile slices: gemm2(slice) consumes hbuf(slice) while it is L3-hot.
    // 1-D grids + XCD-aware decode: a tile's n-chunk blocks share one XCD.
    for (int h0 = 0; h0 < HDIM; h0 += hlen) {
        for (int t0 = 0; t0 < MAXTILE; t0 += TSLICE) {
            int tc = MAXTILE - t0; if (tc > TSLICE) tc = TSLICE;
            gemm1_kernel<<<(hlen / GBN) * tc, 512, 0, stream>>>(
                xbf, w1t, b1, offs, tile_e, tile_m0, list_tok, hbuf, h0, hlen, t0, tc);
            gemm2_kernel<<<(DDIM / GBN2) * tc, 512, 0, stream>>>(
                hbuf, w2t, b2, offs, tile_e, tile_m0, list_tok, list_w,
                ybuf, out, h0, hlen, mode, t0, tc);
        }
    }
    if (mode == 0)
        combine_kernel<<<T_TOK * 64 / 256, 256, 0, stream>>>(ybuf, pos_tk, tok_w, out);
}